// Round 1
// baseline (511.583 us; speedup 1.0000x reference)
//
#include <hip/hip_runtime.h>
#include <math.h>

// ---------------- problem constants ----------------
#define B_    2
#define CIN_  32
#define H_    64
#define W_    64
#define HP_   57
#define WP_   57
#define NP_   (B_*HP_*WP_)     // 6498 patches
#define NVALS_ 31

// workspace layout (floats)
#define XR_OFF   0              // 2*3*64*64   = 24576
#define PAR_OFF  24576          // 2*5*57*57   = 32490
#define FP_OFF   57066          // 2*3*64*64   = 24576 (fold of patches)
#define FG_OFF   81642          // 2*64*64     = 8192  (fold of boundaries)
#define WS_TOTAL 89834

// ---------------- math helpers (faithful to jnp f32 semantics) ----------------
static __device__ __forceinline__ float mod2pi(float x) {
    const float TP = (float)(2.0 * M_PI);
    float m = fmodf(x, TP);
    return (m < 0.0f) ? (m + TP) : m;
}
static __device__ __forceinline__ float pow35f(float t) {
    // x**35 via squaring (matches XLA integer-pow lowering)
    float t2 = t * t, t4 = t2 * t2, t8 = t4 * t4, t16 = t8 * t8, t32 = t16 * t16;
    return t32 * t2 * t;
}
static __device__ __forceinline__ float siluf(float x) {
    return x / (1.0f + expf(-x));   // x * sigmoid(x)
}

struct Geo {
    float s1, c1, s2, c2, s3, c3, s4, c4;
    float sgn13, sgn42, g13, g42, x0, y0;
};

static __device__ void setup_geo(const float p[5], Geo& G) {
    const float PIF = (float)M_PI;
    float m0 = mod2pi(p[0]), m1 = mod2pi(p[1]), m2 = mod2pi(p[2]);
    // exact sort of 3 (median via min/max network)
    float lo = fminf(m0, m1), hi = fmaxf(m0, m1);
    float a1 = fminf(lo, m2);
    float a3 = fmaxf(hi, m2);
    float a2 = fmaxf(fminf(hi, m2), lo);
    float hm = mod2pi(0.5f * (a1 - a3));
    float a4 = 0.5f * (a1 + a3) + ((hm >= PIF) ? PIF : 0.0f);
    float d42 = mod2pi(a2 - a4);
    G.sgn42 = (d42 < PIF) ? 1.0f : -1.0f;
    G.g42 = pow35f(d42 / PIF - 1.0f) * 0.1f;   // g(d)*TAU
    float d13 = mod2pi(a3 - a1);
    G.sgn13 = (d13 < PIF) ? 1.0f : -1.0f;
    G.g13 = pow35f(d13 / PIF - 1.0f) * 0.1f;
    G.s1 = sinf(a1); G.c1 = cosf(a1);
    G.s2 = sinf(a2); G.c2 = cosf(a2);
    G.s3 = sinf(a3); G.c3 = cosf(a3);
    G.s4 = sinf(a4); G.c4 = cosf(a4);
    G.x0 = p[3]; G.y0 = p[4];
}

static __device__ __forceinline__ void dists_at(const Geo& G, float xg, float yg,
                                                float& d13, float& d42) {
    float dx = xg - G.x0, dy = yg - G.y0;
    float l1 = -G.s1 * dx + G.c1 * dy;
    float l2 = -G.s2 * dx + G.c2 * dy;
    float l3 = -G.s3 * dx + G.c3 * dy;
    float l4 = -G.s4 * dx + G.c4 * dy;
    d13 = G.sgn13 * fminf(G.sgn13 * l1, -(G.sgn13 * l3)) + G.g13;
    d42 = G.sgn42 * fminf(G.sgn42 * l4, -(G.sgn42 * l2)) + G.g42;
}

static __device__ __forceinline__ void wedge_at(const Geo& G, float xg, float yg,
                                                float& w0, float& w1, float& w2,
                                                float& d13o, float& d42o) {
    const float C2OPI  = (float)(2.0 / M_PI);
    const float INVETA = (float)(1.0 / (double)((float)0.01));  // 1/ETA
    float d13, d42;
    dists_at(G, xg, yg, d13, d42);
    float hd0 = 0.5f * (1.0f + C2OPI * atanf(d13 * INVETA));
    float hd1 = 0.5f * (1.0f + C2OPI * atanf(d42 * INVETA));
    w0 = 1.0f - hd0;
    w1 = hd0 * (1.0f - hd1);
    w2 = hd0 * hd1;
    d13o = d13; d42o = d42;
}

// ---------------- kernel A: conv1x1 + BN + SiLU -> xr ----------------
__global__ __launch_bounds__(256) void head_in_kernel(const float* __restrict__ x,
                                                      const float* __restrict__ rw,
                                                      const float* __restrict__ gamma,
                                                      const float* __restrict__ beta,
                                                      float* __restrict__ xr) {
    const int o = blockIdx.x;           // output channel 0..2
    const int t = threadIdx.x;
    __shared__ float ssum[256], ssq[256];
    __shared__ float s_scale, s_shift;

    float lsum = 0.0f, lsq = 0.0f;
    for (int e = t; e < B_ * 4096; e += 256) {
        int bb = e >> 12, rem = e & 4095;
        const float* xp = x + (size_t)bb * CIN_ * 4096 + rem;
        float acc = 0.0f;
#pragma unroll
        for (int c = 0; c < CIN_; ++c) acc += rw[o * CIN_ + c] * xp[c * 4096];
        xr[(bb * 3 + o) * 4096 + rem] = acc;
        lsum += acc; lsq += acc * acc;
    }
    ssum[t] = lsum; ssq[t] = lsq;
    __syncthreads();
    for (int s = 128; s > 0; s >>= 1) {
        if (t < s) { ssum[t] += ssum[t + s]; ssq[t] += ssq[t + s]; }
        __syncthreads();
    }
    if (t == 0) {
        float mean = ssum[0] / 8192.0f;
        float var  = ssq[0] / 8192.0f - mean * mean;
        float sc = gamma[o] / sqrtf(var + 1e-5f);
        s_scale = sc;
        s_shift = beta[o] - mean * sc;
    }
    __syncthreads();
    float sc = s_scale, sh = s_shift;
    for (int e = t; e < B_ * 4096; e += 256) {
        int bb = e >> 12, rem = e & 4095;
        int idx = (bb * 3 + o) * 4096 + rem;
        float v = xr[idx] * sc + sh;
        xr[idx] = siluf(v);
    }
}

// ---------------- kernel B: one coordinate-descent step ----------------
// thread = (patch, candidate). 32 threads/patch (31 candidates + 1 pad).
__global__ __launch_bounds__(256) void step_kernel(const float* __restrict__ xr,
                                                   float* __restrict__ params,
                                                   int stepIdx) {
    __shared__ float s_img[8][192];   // 8 patch-groups per block, [c*64 + pix]
    __shared__ float s_lin[8];
    const int t = threadIdx.x;
    if (t < 8) s_lin[t] = (float)(-1.0 + (double)t * (2.0 / 7.0));

    const int cand = t & 31;
    const int lg = t >> 5;                       // group in block, 0..7
    const int patch = blockIdx.x * 8 + lg;
    const bool active = (patch < NP_);
    int b = 0, hp = 0, wp = 0;
    if (active) {
        b = patch / (HP_ * WP_);
        int pi = patch - b * (HP_ * WP_);
        hp = pi / WP_; wp = pi - hp * WP_;
        for (int idx = cand; idx < 192; idx += 32) {
            int c = idx >> 6, pix = idx & 63;
            int pr = pix >> 3, pc = pix & 7;
            s_img[lg][idx] = xr[((b * 3 + c) << 12) + ((hp + pr) << 6) + (wp + pc)];
        }
    }
    __syncthreads();
    if (!active) return;

    float p[5];
#pragma unroll
    for (int j = 0; j < 5; ++j) p[j] = params[((b * 5 + j) * HP_ + hp) * WP_ + wp];
    const float base = p[stepIdx];
    const int ci = (cand < NVALS_) ? cand : (NVALS_ - 1);
    float add;
    if (stepIdx < 3) add = (float)((double)ci * (6.283185307179586476925286766559 / 31.0));
    else             add = (float)(-3.0 + (double)ci * 0.2);
    p[stepIdx] = base + add;

    Geo G; setup_geo(p, G);
    const float* img = s_img[lg];

    // pass 1: accumulate wedge sums and color numerators
    float ws0 = 0.0f, ws1 = 0.0f, ws2 = 0.0f;
    float cn[3][3] = {{0,0,0},{0,0,0},{0,0,0}};
    for (int pix = 0; pix < 64; ++pix) {
        float xg = s_lin[pix & 7], yg = s_lin[pix >> 3];
        float w0, w1, w2, du0, du1;
        wedge_at(G, xg, yg, w0, w1, w2, du0, du1);
        ws0 += w0; ws1 += w1; ws2 += w2;
        float i0 = img[pix], i1 = img[64 + pix], i2 = img[128 + pix];
        cn[0][0] += i0 * w0; cn[0][1] += i0 * w1; cn[0][2] += i0 * w2;
        cn[1][0] += i1 * w0; cn[1][1] += i1 * w1; cn[1][2] += i1 * w2;
        cn[2][0] += i2 * w0; cn[2][1] += i2 * w1; cn[2][2] += i2 * w2;
    }
    float col[3][3];
#pragma unroll
    for (int c = 0; c < 3; ++c) {
        col[c][0] = cn[c][0] / (ws0 + 1e-10f);
        col[c][1] = cn[c][1] / (ws1 + 1e-10f);
        col[c][2] = cn[c][2] / (ws2 + 1e-10f);
    }
    // pass 2: reconstruction loss (matches reference computation)
    float loss = 0.0f;
    for (int pix = 0; pix < 64; ++pix) {
        float xg = s_lin[pix & 7], yg = s_lin[pix >> 3];
        float w0, w1, w2, du0, du1;
        wedge_at(G, xg, yg, w0, w1, w2, du0, du1);
        float i0 = img[pix], i1 = img[64 + pix], i2 = img[128 + pix];
        float p0 = w0 * col[0][0] + w1 * col[0][1] + w2 * col[0][2];
        float p1 = w0 * col[1][0] + w1 * col[1][1] + w2 * col[1][2];
        float p2 = w0 * col[2][0] + w1 * col[2][1] + w2 * col[2][2];
        float d0 = i0 - p0, d1 = i1 - p1, d2 = i2 - p2;
        loss += d0 * d0 + d1 * d1 + d2 * d2;
    }
    loss *= (1.0f / 64.0f);
    if (cand >= NVALS_) loss = INFINITY;

    // argmin over 31 candidates within the 32-lane group (first-index tie-break)
    float bl = loss; int bi = cand;
    for (int off = 16; off > 0; off >>= 1) {
        float ol = __shfl_down(bl, (unsigned)off, 32);
        int   oi = __shfl_down(bi, (unsigned)off, 32);
        if (ol < bl || (ol == bl && oi < bi)) { bl = ol; bi = oi; }
    }
    if (cand == 0) {
        float badd;
        if (stepIdx < 3) badd = (float)((double)bi * (6.283185307179586476925286766559 / 31.0));
        else             badd = (float)(-3.0 + (double)bi * 0.2);
        params[((b * 5 + stepIdx) * HP_ + hp) * WP_ + wp] = base + badd;
    }
}

// ---------------- kernel C: finalize + fold (wave per patch, lane = pixel) ---
__global__ __launch_bounds__(256) void finalize_kernel(const float* __restrict__ xr,
                                                       const float* __restrict__ params,
                                                       float* __restrict__ foldP,
                                                       float* __restrict__ foldG) {
    __shared__ float s_lin[8];
    if (threadIdx.x < 8) s_lin[threadIdx.x] = (float)(-1.0 + (double)threadIdx.x * (2.0 / 7.0));
    __syncthreads();

    const int lane = threadIdx.x & 63;
    const int wave = (blockIdx.x * 256 + threadIdx.x) >> 6;
    if (wave >= NP_) return;
    const int b = wave / (HP_ * WP_);
    int pi = wave - b * (HP_ * WP_);
    const int hp = pi / WP_, wp = pi - hp * WP_;

    float p[5];
#pragma unroll
    for (int j = 0; j < 5; ++j) p[j] = params[((b * 5 + j) * HP_ + hp) * WP_ + wp];
    Geo G; setup_geo(p, G);

    const int pr = lane >> 3, pc = lane & 7;
    float xg = s_lin[pc], yg = s_lin[pr];
    float w0, w1, w2, d13, d42;
    wedge_at(G, xg, yg, w0, w1, w2, d13, d42);
    float i0 = xr[((b * 3 + 0) << 12) + ((hp + pr) << 6) + (wp + pc)];
    float i1 = xr[((b * 3 + 1) << 12) + ((hp + pr) << 6) + (wp + pc)];
    float i2 = xr[((b * 3 + 2) << 12) + ((hp + pr) << 6) + (wp + pc)];

    float r[12] = { w0, w1, w2,
                    i0 * w0, i0 * w1, i0 * w2,
                    i1 * w0, i1 * w1, i1 * w2,
                    i2 * w0, i2 * w1, i2 * w2 };
#pragma unroll
    for (int m = 1; m < 64; m <<= 1) {
#pragma unroll
        for (int j = 0; j < 12; ++j) r[j] += __shfl_xor(r[j], m);
    }
    float col[3][3];
#pragma unroll
    for (int c = 0; c < 3; ++c) {
        col[c][0] = r[3 + c * 3 + 0] / (r[0] + 1e-10f);
        col[c][1] = r[3 + c * 3 + 1] / (r[1] + 1e-10f);
        col[c][2] = r[3 + c * 3 + 2] / (r[2] + 1e-10f);
    }
    float o0 = w0 * col[0][0] + w1 * col[0][1] + w2 * col[0][2];
    float o1 = w0 * col[1][0] + w1 * col[1][1] + w2 * col[1][2];
    float o2 = w0 * col[2][0] + w1 * col[2][1] + w2 * col[2][2];

    float mad = (d13 < 0.0f) ? -d13 : ((d42 < 0.0f) ? fminf(d13, -d42) : fminf(d13, d42));
    float tt = mad / 0.05f;          // mad / DELTA
    float lb = 1.0f / (1.0f + tt * tt);

    const int off = ((hp + pr) << 6) + (wp + pc);
    atomicAdd(&foldP[(b * 3 + 0) * 4096 + off], o0);
    atomicAdd(&foldP[(b * 3 + 1) * 4096 + off], o1);
    atomicAdd(&foldP[(b * 3 + 2) * 4096 + off], o2);
    atomicAdd(&foldG[b * 4096 + off], lb);
}

// ---------------- kernel D: heads (conv1x1 + BN + SiLU) ----------------
static __device__ __forceinline__ float np_count(int tpos) {
    int lo = (tpos - 56 > 0) ? (tpos - 56) : 0;
    int hi = (tpos < 7) ? tpos : 7;
    return (float)(hi - lo + 1);
}

__global__ __launch_bounds__(256) void head_out_kernel(const float* __restrict__ foldP,
                                                       const float* __restrict__ foldG,
                                                       const float* __restrict__ fb_w,
                                                       const float* __restrict__ fb_g,
                                                       const float* __restrict__ fb_b,
                                                       const float* __restrict__ fi_w,
                                                       const float* __restrict__ fi_g,
                                                       const float* __restrict__ fi_b,
                                                       float* __restrict__ out) {
    const int which = blockIdx.x;   // 0 = boundaries, 1 = image
    const int t = threadIdx.x;
    __shared__ float ssum[256], ssq[256];
    __shared__ float s_scale, s_shift;

    float lsum = 0.0f, lsq = 0.0f;
    for (int e = t; e < B_ * 4096; e += 256) {
        int b = e >> 12, h = (e >> 6) & 63, w = e & 63;
        float npv = np_count(h) * np_count(w);
        float v;
        if (which == 0) {
            float gv = foldG[e] / npv;
            v = fb_w[0] * gv + fb_w[1] * gv + fb_w[2] * gv;
        } else {
            int off = (h << 6) + w;
            float s0 = foldP[(b * 3 + 0) * 4096 + off] / npv;
            float s1 = foldP[(b * 3 + 1) * 4096 + off] / npv;
            float s2 = foldP[(b * 3 + 2) * 4096 + off] / npv;
            v = fi_w[0] * s0 + fi_w[1] * s1 + fi_w[2] * s2;
        }
        lsum += v; lsq += v * v;
    }
    ssum[t] = lsum; ssq[t] = lsq;
    __syncthreads();
    for (int s = 128; s > 0; s >>= 1) {
        if (t < s) { ssum[t] += ssum[t + s]; ssq[t] += ssq[t + s]; }
        __syncthreads();
    }
    if (t == 0) {
        float mean = ssum[0] / 8192.0f;
        float var  = ssq[0] / 8192.0f - mean * mean;
        float g = (which == 0) ? fb_g[0] : fi_g[0];
        float be = (which == 0) ? fb_b[0] : fi_b[0];
        float sc = g / sqrtf(var + 1e-5f);
        s_scale = sc;
        s_shift = be - mean * sc;
    }
    __syncthreads();
    float sc = s_scale, sh = s_shift;
    const int obase = which * 8192;
    for (int e = t; e < B_ * 4096; e += 256) {
        int b = e >> 12, h = (e >> 6) & 63, w = e & 63;
        float npv = np_count(h) * np_count(w);
        float v;
        if (which == 0) {
            float gv = foldG[e] / npv;
            v = fb_w[0] * gv + fb_w[1] * gv + fb_w[2] * gv;
        } else {
            int off = (h << 6) + w;
            float s0 = foldP[(b * 3 + 0) * 4096 + off] / npv;
            float s1 = foldP[(b * 3 + 1) * 4096 + off] / npv;
            float s2 = foldP[(b * 3 + 2) * 4096 + off] / npv;
            v = fi_w[0] * s0 + fi_w[1] * s1 + fi_w[2] * s2;
        }
        float y = v * sc + sh;
        out[obase + e] = siluf(y);
    }
}

// ---------------- launch ----------------
extern "C" void kernel_launch(void* const* d_in, const int* in_sizes, int n_in,
                              void* d_out, int out_size, void* d_ws, size_t ws_size,
                              hipStream_t stream) {
    (void)in_sizes; (void)n_in; (void)out_size; (void)ws_size;
    const float* x        = (const float*)d_in[0];
    const float* reduce_w = (const float*)d_in[1];
    const float* reduce_g = (const float*)d_in[2];
    const float* reduce_b = (const float*)d_in[3];
    const float* fb_w     = (const float*)d_in[4];
    const float* fb_g     = (const float*)d_in[5];
    const float* fb_b     = (const float*)d_in[6];
    const float* fi_w     = (const float*)d_in[7];
    const float* fi_g     = (const float*)d_in[8];
    const float* fi_b     = (const float*)d_in[9];
    float* ws     = (float*)d_ws;
    float* xr     = ws + XR_OFF;
    float* params = ws + PAR_OFF;
    float* foldP  = ws + FP_OFF;
    float* foldG  = ws + FG_OFF;
    float* out    = (float*)d_out;

    // zero params + fold accumulators (contiguous region)
    hipMemsetAsync(params, 0, (size_t)(WS_TOTAL - PAR_OFF) * sizeof(float), stream);

    head_in_kernel<<<3, 256, 0, stream>>>(x, reduce_w, reduce_g, reduce_b, xr);
    for (int i = 0; i < 5; ++i)
        step_kernel<<<(NP_ + 7) / 8, 256, 0, stream>>>(xr, params, i);
    finalize_kernel<<<(NP_ + 3) / 4, 256, 0, stream>>>(xr, params, foldP, foldG);
    head_out_kernel<<<2, 256, 0, stream>>>(foldP, foldG, fb_w, fb_g, fb_b,
                                           fi_w, fi_g, fi_b, out);
}